// Round 17
// baseline (193.372 us; speedup 1.0000x reference)
//
#include <hip/hip_runtime.h>
#include <hip/hip_bf16.h>

typedef __attribute__((ext_vector_type(8))) short short8;
typedef __attribute__((ext_vector_type(4))) short short4e;
typedef __attribute__((ext_vector_type(4))) float f32x4;
typedef __attribute__((ext_vector_type(16))) float f32x16;
typedef __attribute__((ext_vector_type(4))) unsigned uint4v;

#define SC_LOG2E 0.04508422f   // (1/32) * log2(e)
#define MFMA32(a, b, c) __builtin_amdgcn_mfma_f32_32x32x16_bf16(a, b, c, 0, 0, 0)

__device__ inline short bf16r(float f) {
    union { float f; unsigned u; } v; v.f = f;
    unsigned r = v.u + 0x7FFFu + ((v.u >> 16) & 1u);
    return (short)(r >> 16);
}
__device__ inline float bflo(unsigned u) {
    union { unsigned u; float f; } v; v.u = u << 16; return v.f;
}
__device__ inline float bfhi(unsigned u) {
    union { unsigned u; float f; } v; v.u = u & 0xffff0000u; return v.f;
}
// fast 2^x: single v_exp_f32, no libm range fixup (|x| < 40 in all our uses)
#if __has_builtin(__builtin_amdgcn_exp2f)
__device__ inline float fexp2(float x) { return __builtin_amdgcn_exp2f(x); }
#else
__device__ inline float fexp2(float x) { return __expf(x * 0.6931471806f); }
#endif
__device__ inline unsigned cvt_pk_bf16(float lo, float hi) {
    unsigned r;
    asm("v_cvt_pk_bf16_f32 %0, %1, %2" : "=v"(r) : "v"(lo), "v"(hi));
    return r;
}
// exchanges a.hi(lanes32-63) <-> b.lo(lanes0-31): a'=[a.lo,b.lo], b'=[a.hi,b.hi]
__device__ inline void perm32swap(unsigned& a, unsigned& b) {
    asm("v_permlane32_swap_b32 %0, %1" : "+v"(a), "+v"(b));
}

#define GLOAD_LDS16(gp, lp) __builtin_amdgcn_global_load_lds( \
    (const __attribute__((address_space(1))) unsigned int*)(gp), \
    (__attribute__((address_space(3))) unsigned int*)(lp), 16, 0, 0)

#define WB10 do { asm volatile("s_waitcnt vmcnt(10)\ns_barrier" ::: "memory"); __builtin_amdgcn_sched_barrier(0); } while (0)
#define WB4  do { asm volatile("s_waitcnt vmcnt(4)\ns_barrier"  ::: "memory"); __builtin_amdgcn_sched_barrier(0); } while (0)
#define WB0  do { asm volatile("s_waitcnt vmcnt(0)\ns_barrier"  ::: "memory"); __builtin_amdgcn_sched_barrier(0); } while (0)

// ---------------- elementwise cast fp32 -> bf16 ----------------
__global__ void castk(const float* __restrict__ in, short* __restrict__ out, int n4) {
    int i = blockIdx.x * 256 + threadIdx.x;
    if (i < n4) {
        float4 v = ((const float4*)in)[i];
        short4 o;
        o.x = bf16r(v.x); o.y = bf16r(v.y); o.z = bf16r(v.z); o.w = bf16r(v.w);
        ((short4*)out)[i] = o;
    }
}

// ---------------- transpose-cast fp32[R][C] -> bf16[C][R], rows < nscale scaled ----------------
__global__ void tcast(const float* __restrict__ src, short* __restrict__ dst, int R, int C,
                      int nscale, float sfac) {
    __shared__ float tile[32][33];
    int bi = blockIdx.x, bj = blockIdx.y;
    int tx = threadIdx.x & 31, ty = threadIdx.x >> 5;
#pragma unroll
    for (int p = 0; p < 4; p++)
        tile[ty + p * 8][tx] = src[(long)(bi * 32 + ty + p * 8) * C + bj * 32 + tx];
    __syncthreads();
#pragma unroll
    for (int p = 0; p < 4; p++) {
        int n = bj * 32 + ty + p * 8;                  // output channel (source column)
        float v = tile[tx][ty + p * 8];
        if (n < nscale) v *= sfac;
        dst[(long)n * R + bi * 32 + tx] = bf16r(v);
    }
}

// ---------------- gemm256: QKV projection, 256x256 tile, BK=64, 8-phase counted-vmcnt ------
// 512 thr = 8 waves (wm 2 x wn 4), per-wave out 128x64. LDS 128KB: per matrix 2 bufs x
// 2 k-halves x [256 rows][32 k] with chunk-XOR swizzle (phys16B = logical ^ ((row>>2)&3)),
// read banks 2-way (free); staging 1KB-contiguous dests, pre-swizzled per-lane SOURCE.
// Schedule (derived): region(tile,khalf) staged 5-6 phases before use, dies 2 phases before
// overwrite -> uniform vmcnt(10)+s_barrier per phase, 16 MFMA/phase; tail i==7: p4/5
// vmcnt(4), p6/7 vmcnt(0). Epilogue: Q/K cols -> qkv row-major; V cols -> Vt transposed
// (packed short4, acc regs r=0..3 are 4 consecutive k).
__global__ __launch_bounds__(512, 2)
void gemm256(const short* __restrict__ A, const short* __restrict__ Bt,
             short* __restrict__ qkv, short* __restrict__ Vt) {
    __shared__ short lds[65536];
    const int wg = blockIdx.x;
    const int lg = (wg & 7) * 48 + (wg >> 3);          // 384 blocks, bijective XCD chunk
    const int bx = lg % 12, by = lg / 12;
    const int m0 = by * 256, n0 = bx * 256;
    const int tid = threadIdx.x, w = tid >> 6, lane = tid & 63;
    const int wm = w >> 2, wn = w & 3;
    const int l15 = lane & 15, lhi = lane >> 4;
    f32x4 acc[8][4] = {};

    auto stA = [&](int t, int ks) {
#pragma unroll
        for (int j = 0; j < 2; j++) {
            int c = j * 512 + tid;
            int row = c >> 2, sl = c & 3;
            GLOAD_LDS16(A + (long)(m0 + row) * 1024 + t * 64 + ks * 32 + ((sl ^ ((row >> 2) & 3)) * 8),
                        &lds[((t & 1) * 2 + ks) * 8192 + c * 8]);
        }
    };
    auto stB = [&](int t, int ks) {
#pragma unroll
        for (int j = 0; j < 2; j++) {
            int c = j * 512 + tid;
            int row = c >> 2, sl = c & 3;
            GLOAD_LDS16(Bt + (long)(n0 + row) * 1024 + t * 64 + ks * 32 + ((sl ^ ((row >> 2) & 3)) * 8),
                        &lds[32768 + ((t & 1) * 2 + ks) * 8192 + c * 8]);
        }
    };

    short8 af[8], bf[2];
    auto ldA = [&](int buf, int ks) {
#pragma unroll
        for (int fi = 0; fi < 8; fi++) {
            int row = wm * 128 + fi * 16 + l15;
            af[fi] = *(const short8*)(&lds[(buf * 2 + ks) * 8192 + row * 32 +
                                           ((lhi ^ ((row >> 2) & 3)) * 8)]);
        }
    };
    auto ldB = [&](int buf, int ks, int fh) {
#pragma unroll
        for (int u = 0; u < 2; u++) {
            int row = wn * 64 + (fh * 2 + u) * 16 + l15;
            bf[u] = *(const short8*)(&lds[32768 + (buf * 2 + ks) * 8192 + row * 32 +
                                          ((lhi ^ ((row >> 2) & 3)) * 8)]);
        }
    };
    auto mm = [&](int fh) {
        __builtin_amdgcn_s_setprio(1);
#pragma unroll
        for (int fi = 0; fi < 8; fi++)
#pragma unroll
            for (int u = 0; u < 2; u++)
                acc[fi][fh * 2 + u] = __builtin_amdgcn_mfma_f32_16x16x32_bf16(
                    af[fi], bf[u], acc[fi][fh * 2 + u], 0, 0, 0);
        __builtin_amdgcn_s_setprio(0);
    };

    // prologue: mirrors steady-state phases 2..7 of iteration -1 (order matters for vmcnt)
    stA(0, 0); stB(0, 0); stA(0, 1); stB(0, 1); stA(1, 0); stB(1, 0);

    for (int i = 0; i < 8; i++) {
        const int t0 = 2 * i;
        // p0: compute tile t0 ks0 fj-half0
        stA(t0 + 1, 1); WB10;
        ldA(0, 0); ldB(0, 0, 0); mm(0);
        // p1
        stB(t0 + 1, 1); WB10;
        ldB(0, 0, 1); mm(1);
        // p2: tile t0 ks1
        if (i < 7) stA(t0 + 2, 0);
        WB10;
        ldA(0, 1); ldB(0, 1, 0); mm(0);
        // p3
        if (i < 7) stB(t0 + 2, 0);
        WB10;
        ldB(0, 1, 1); mm(1);
        // p4: tile t0+1 ks0
        if (i < 7) { stA(t0 + 2, 1); WB10; } else { WB4; }
        ldA(1, 0); ldB(1, 0, 0); mm(0);
        // p5
        if (i < 7) { stB(t0 + 2, 1); WB10; } else { WB4; }
        ldB(1, 0, 1); mm(1);
        // p6: tile t0+1 ks1
        if (i < 7) { stA(t0 + 3, 0); WB10; } else { WB0; }
        ldA(1, 1); ldB(1, 1, 0); mm(0);
        // p7
        if (i < 7) { stB(t0 + 3, 0); WB10; } else { WB0; }
        ldB(1, 1, 1); mm(1);
    }

    if (n0 >= 2048) {
        // V columns -> Vt[a][col'][k] directly (replaces vtrans)
        const int a = m0 >> 10, k0v = m0 & 1023;
#pragma unroll
        for (int fi = 0; fi < 8; fi++)
#pragma unroll
            for (int fj = 0; fj < 4; fj++) {
                int colp = n0 - 2048 + wn * 64 + fj * 16 + l15;
                int k = k0v + wm * 128 + fi * 16 + lhi * 4;
                short4e s4;
#pragma unroll
                for (int r = 0; r < 4; r++) s4[r] = bf16r(acc[fi][fj][r]);
                *(short4e*)(Vt + (long)a * 1048576 + (long)colp * 1024 + k) = s4;
            }
    } else {
#pragma unroll
        for (int fi = 0; fi < 8; fi++)
#pragma unroll
            for (int fj = 0; fj < 4; fj++)
#pragma unroll
                for (int r = 0; r < 4; r++) {
                    int row = m0 + wm * 128 + fi * 16 + lhi * 4 + r;
                    int col = n0 + wn * 64 + fj * 16 + l15;
                    qkv[(long)row * 3072 + col] = bf16r(acc[fi][fj][r]);
                }
    }
}

// ---------------- bf16 GEMM (128^2, R16-proven): used for the output projection -----------
template<int OUT_BF16>
__global__ __launch_bounds__(256, 3)
void gemm_bt(const short* __restrict__ A, const short* __restrict__ Bt,
             void* __restrict__ Cout, const float* __restrict__ bias,
             int M, int N, int K, int nbx, int cpx, int lda) {
    __shared__ short As[3][128 * 32];
    __shared__ short Bs[3][128 * 32];
    const int wg = blockIdx.x;
    const int lg = (wg & 7) * cpx + (wg >> 3);
    const int bx = lg % nbx, by = lg / nbx;
    const int tid = threadIdx.x, w = tid >> 6, lane = tid & 63;
    const int wr = w >> 1, wc = w & 1;
    const int l15 = lane & 15, lhi = lane >> 4;
    const int m0 = by * 128, n0 = bx * 128;
    f32x4 acc[4][4] = {};
    const int NT = K / 32;

    auto stage = [&](int buf, int t) {
        int k0 = t * 32;
#pragma unroll
        for (int j = 0; j < 2; j++) {
            int chunk = w * 128 + j * 64 + lane;
            int row = chunk >> 2, cp = chunk & 3;
            int cc = cp ^ ((row >> 1) & 3);            // pre-swizzled global k-chunk
            GLOAD_LDS16(A  + (long)(m0 + row) * lda + k0 + cc * 8, &As[buf][chunk * 8]);
            GLOAD_LDS16(Bt + (long)(n0 + row) * K   + k0 + cc * 8, &Bs[buf][chunk * 8]);
        }
    };

    stage(0, 0);
    stage(1, 1);
    asm volatile("s_waitcnt vmcnt(4)\ns_barrier" ::: "memory");
    __builtin_amdgcn_sched_barrier(0);

    int bR = 0, bW = 2;
    for (int t = 0; t < NT; t++) {
        bool issued = (t + 2 < NT);
        if (issued) stage(bW, t + 2);
        const short* Ab = As[bR];
        const short* Bb = Bs[bR];
        short8 af[4], bfr[4];
#pragma unroll
        for (int i = 0; i < 4; i++) {
            int arow = wr * 64 + i * 16 + l15;
            int brow = wc * 64 + i * 16 + l15;
            af[i]  = *(const short8*)(Ab + arow * 32 + (lhi ^ ((arow >> 1) & 3)) * 8);
            bfr[i] = *(const short8*)(Bb + brow * 32 + (lhi ^ ((brow >> 1) & 3)) * 8);
        }
        __builtin_amdgcn_s_setprio(1);
#pragma unroll
        for (int i = 0; i < 4; i++)
#pragma unroll
            for (int j = 0; j < 4; j++)
                acc[i][j] = __builtin_amdgcn_mfma_f32_16x16x32_bf16(af[i], bfr[j], acc[i][j], 0, 0, 0);
        __builtin_amdgcn_s_setprio(0);
        if (issued) asm volatile("s_waitcnt vmcnt(4)\ns_barrier" ::: "memory");
        else        asm volatile("s_waitcnt vmcnt(0)\ns_barrier" ::: "memory");
        __builtin_amdgcn_sched_barrier(0);
        bR = (bR == 2) ? 0 : bR + 1;
        bW = (bW == 2) ? 0 : bW + 1;
    }
#pragma unroll
    for (int i = 0; i < 4; i++)
#pragma unroll
        for (int j = 0; j < 4; j++)
#pragma unroll
            for (int r = 0; r < 4; r++) {
                int row = m0 + wr * 64 + i * 16 + lhi * 4 + r;
                int col = n0 + wc * 64 + j * 16 + l15;
                float v = acc[i][j][r];
                if (OUT_BF16) ((short*)Cout)[(long)row * N + col] = bf16r(v);
                else          ((float*)Cout)[(long)row * N + col] = v + bias[col];
            }
}

// ---------------- Phase A: negL packed-bf16 pairs, fragment-major ----------------
// word u of frag (a,ktg,qtg,lane): lo=-log2 D at reg 2u, hi at reg 2u+1;
// reg r -> (k = ktg*32 + (r&3)+8*(r>>2)+4*(lane>>5), q = qtg*32 + (lane&31))
__global__ __launch_bounds__(256, 2)
void dsum_kernel(const short* __restrict__ qkv, unsigned* __restrict__ negL) {
    __shared__ short Qs[2][128 * 64];
    __shared__ short Ks[2][128 * 64];
    const int wg = blockIdx.x;
    const int lg = (wg & 7) * 64 + (wg >> 3);
    const int a = lg >> 6, q0 = ((lg >> 3) & 7) * 128, k0 = (lg & 7) * 128;
    const int tid = threadIdx.x, w = tid >> 6, lane = tid & 63;
    const int wr = w >> 1, wc = w & 1;                 // wr: k-half, wc: q-half
    const int l31 = lane & 31, hi = lane >> 5;
    const long qb = (long)a * 3145728;
    f32x16 dacc[2][2] = {};

    auto stage = [&](int buf, int hh) {
#pragma unroll
        for (int j = 0; j < 4; j++) {
            int c = j * 256 + tid;
            int row = c >> 3, cc = (c & 7) ^ (row & 7);
            GLOAD_LDS16(qkv + qb + (long)(q0 + row) * 3072 + hh * 64 + cc * 8,        &Qs[buf][c * 8]);
            GLOAD_LDS16(qkv + qb + (long)(k0 + row) * 3072 + 1024 + hh * 64 + cc * 8, &Ks[buf][c * 8]);
        }
    };

    stage(0, 0);
    __syncthreads();
    int buf = 0;
    for (int hh = 0; hh < 16; hh++) {
        if (hh < 15) stage(buf ^ 1, hh + 1);
        short8 ka[2][4], qf[2][4];
#pragma unroll
        for (int i = 0; i < 2; i++)
#pragma unroll
            for (int dc = 0; dc < 4; dc++) {
                int row = wr * 64 + i * 32 + l31;
                int ph = (dc * 2 + hi) ^ (row & 7);
                ka[i][dc] = *(const short8*)(&Ks[buf][row * 64 + ph * 8]);
            }
#pragma unroll
        for (int j = 0; j < 2; j++)
#pragma unroll
            for (int dc = 0; dc < 4; dc++) {
                int row = wc * 64 + j * 32 + l31;
                int ph = (dc * 2 + hi) ^ (row & 7);
                qf[j][dc] = *(const short8*)(&Qs[buf][row * 64 + ph * 8]);
            }
#pragma unroll
        for (int i = 0; i < 2; i++)
#pragma unroll
            for (int j = 0; j < 2; j++) {
                f32x16 s = {};
#pragma unroll
                for (int dc = 0; dc < 4; dc++)
                    s = MFMA32(ka[i][dc], qf[j][dc], s);
#pragma unroll
                for (int r = 0; r < 16; r++)
                    dacc[i][j][r] += fexp2(s[r]);      // Q pre-scaled: s already log2-domain
            }
        __syncthreads();
        buf ^= 1;
    }
#pragma unroll
    for (int i = 0; i < 2; i++)
#pragma unroll
        for (int j = 0; j < 2; j++) {
            int ktg = (k0 >> 5) + wr * 2 + i;
            int qtg = (q0 >> 5) + wc * 2 + j;
            unsigned pwv[8];
#pragma unroll
            for (int u = 0; u < 8; u++)
                pwv[u] = cvt_pk_bf16(-__log2f(dacc[i][j][2 * u]),
                                     -__log2f(dacc[i][j][2 * u + 1]));
            unsigned* dst = negL + (((long)(a * 32 + ktg) * 32 + qtg) << 9) + lane * 8;
            *(uint4v*)dst       = (uint4v){pwv[0], pwv[1], pwv[2], pwv[3]};
            *(uint4v*)(dst + 4) = (uint4v){pwv[4], pwv[5], pwv[6], pwv[7]};
        }
}

// ---------------- Phase B: shared fragment-order staging + depth-2 counted-vmcnt ----------
__global__ __launch_bounds__(256, 2)
void attn2_kernel(const short* __restrict__ qkv, const short* __restrict__ Vt,
                  const unsigned* __restrict__ negL, short* __restrict__ ctx) {
    __shared__ short lds[3 * 8192];
    const int wg = blockIdx.x;
    const int lg = (wg & 7) * 64 + (wg >> 3);          // one batch per XCD
    const int a = lg >> 6, h = (lg >> 2) & 15, qblk = lg & 3;
    const int tid = threadIdx.x, w = tid >> 6, lane = tid & 63;
    const int l31 = lane & 31, hi = lane >> 5;
    const int qw = qblk * 256 + w * 64;
    const long qb = (long)a * 3145728;

    // Q fragments (B-operand, pre-scaled by (1/32)*log2e at tcast time)
    short8 qfrag[2][4];
#pragma unroll
    for (int qs = 0; qs < 2; qs++)
#pragma unroll
        for (int dc = 0; dc < 4; dc++)
            qfrag[qs][dc] = *(const short8*)(qkv + qb +
                (long)(qw + qs * 32 + l31) * 3072 + h * 64 + dc * 16 + hi * 8);

    const short* kcol  = qkv + qb + 1024 + h * 64;
    const short* vbase = Vt + (long)a * 1048576 + (long)(h * 64) * 1024;
    const unsigned* lbase = negL + (long)a * 524288 + (qw >> 5) * 512 + lane * 8;

    auto stage = [&](int buf, int t) {
        int k0 = t * 64;
#pragma unroll
        for (int j = 0; j < 2; j++) {
            GLOAD_LDS16(kcol + (long)(k0 + j * 32 + l31) * 3072 + w * 16 + hi * 8,
                        &lds[buf * 8192 + (j * 256 + tid) * 8]);
            int fidx = j * 4 + w, n = fidx >> 1, dt = fidx & 1;
            GLOAD_LDS16(vbase + (long)(dt * 32 + l31) * 1024 + k0 + n * 16 + hi * 8,
                        &lds[buf * 8192 + 4096 + (j * 256 + tid) * 8]);
        }
    };

    f32x16 oacc[2][2] = {};   // [qs][dt]
    stage(0, 0);
    stage(1, 1);
    asm volatile("s_waitcnt vmcnt(4)\ns_barrier" ::: "memory");
    __builtin_amdgcn_sched_barrier(0);

    int bR = 0, bW = 2;
    for (int t = 0; t < 16; t++) {
        uint4v dm[2][2][2];
#pragma unroll
        for (int qs = 0; qs < 2; qs++)
#pragma unroll
            for (int kt = 0; kt < 2; kt++) {
                const unsigned* dp = lbase + (long)(t * 2 + kt) * 16384 + qs * 512;
                dm[qs][kt][0] = *(const uint4v*)dp;
                dm[qs][kt][1] = *(const uint4v*)(dp + 4);
            }
        if (t + 2 < 16) stage(bW, t + 2);

        const short* Kb = &lds[bR * 8192];
        const short* Vb = &lds[bR * 8192 + 4096];
#pragma unroll
        for (int kt = 0; kt < 2; kt++) {
            short8 ka[4];
#pragma unroll
            for (int dc = 0; dc < 4; dc++)
                ka[dc] = *(const short8*)(Kb + ((kt * 4 + dc) * 64 + lane) * 8);

            short8 pf[2][2];   // [qs][nn]
#pragma unroll
            for (int qs = 0; qs < 2; qs++) {
                f32x16 s = {};
                __builtin_amdgcn_s_setprio(1);
#pragma unroll
                for (int dc = 0; dc < 4; dc++)
                    s = MFMA32(ka[dc], qfrag[qs][dc], s);
                __builtin_amdgcn_s_setprio(0);
                unsigned pw[8];
#pragma unroll
                for (int u = 0; u < 8; u++) {
                    unsigned d = dm[qs][kt][u >> 2][u & 3];
                    float e0 = fexp2(s[2 * u]     + bflo(d));
                    float e1 = fexp2(s[2 * u + 1] + bfhi(d));
                    pw[u] = cvt_pk_bf16(e0, e1);
                }
                perm32swap(pw[0], pw[2]); perm32swap(pw[1], pw[3]);
                perm32swap(pw[4], pw[6]); perm32swap(pw[5], pw[7]);
                union { uint4v u; short8 s8; } c0, c1;
                c0.u = (uint4v){pw[0], pw[1], pw[2], pw[3]};
                c1.u = (uint4v){pw[4], pw[5], pw[6], pw[7]};
                pf[qs][0] = c0.s8;
                pf[qs][1] = c1.s8;
            }
            __builtin_amdgcn_s_setprio(1);
#pragma unroll
            for (int dt = 0; dt < 2; dt++)
#pragma unroll
                for (int nn = 0; nn < 2; nn++) {
                    short8 vf = *(const short8*)(Vb + (((kt * 2 + nn) * 2 + dt) * 64 + lane) * 8);
#pragma unroll
                    for (int qs = 0; qs < 2; qs++)
                        oacc[qs][dt] = MFMA32(pf[qs][nn], vf, oacc[qs][dt]);
                }
            __builtin_amdgcn_s_setprio(0);
        }
        asm volatile("s_waitcnt vmcnt(4)\ns_barrier" ::: "memory");
        __builtin_amdgcn_sched_barrier(0);
        bR = (bR == 2) ? 0 : bR + 1;
        bW = (bW == 2) ? 0 : bW + 1;
    }
    // epilogue: ctx aliases qkv V-columns (lda 3072)
#pragma unroll
    for (int qs = 0; qs < 2; qs++)
#pragma unroll
        for (int dt = 0; dt < 2; dt++)
#pragma unroll
            for (int r = 0; r < 16; r++) {
                int q = qw + qs * 32 + (r & 3) + 8 * (r >> 2) + 4 * hi;
                int col = h * 64 + dt * 32 + l31;
                ctx[((long)a * 1024 + q) * 3072 + col] = bf16r(oacc[qs][dt][r]);
            }
}

extern "C" void kernel_launch(void* const* d_in, const int* in_sizes, int n_in,
                              void* d_out, int out_size, void* d_ws, size_t ws_size,
                              hipStream_t stream) {
    const float* x     = (const float*)d_in[0];
    const float* w_qkv = (const float*)d_in[1];
    const float* w_out = (const float*)d_in[2];
    const float* b_out = (const float*)d_in[3];
    float* out = (float*)d_out;

    char* ws = (char*)d_ws;
    short* wqkvT   = (short*)(ws);                // [0,6MB)   dead after gemm1
    unsigned* negL = (unsigned*)(ws);             // [0,16MB)  packed bf16 pairs (over wqkvT,
                                                  //           written by dsum AFTER gemm1)
    short* xb    = (short*)(ws + 16777216);       // [16,32MB) x bf16
    short* woT   = (short*)(ws + 33554432);       // [32,34MB) persists to gemm2
    short* qkv   = (short*)(ws + 35651584);       // [34,82MB) qkv bf16 [8192][3072]
    short* Vt    = (short*)(ws + 85983232);       // [82,98MB) V^T bf16 [8][1024][1024]
    short* ctx   = qkv + 2048;                    // aliases qkv V-columns, lda 3072
    if (ws_size < 109051904u) return;

    castk<<<8192, 256, 0, stream>>>(x, xb, 2097152);
    tcast<<<dim3(32, 96), 256, 0, stream>>>(w_qkv, wqkvT, 1024, 3072, 1024, SC_LOG2E);
    tcast<<<dim3(32, 32), 256, 0, stream>>>(w_out, woT, 1024, 1024, 0, 1.0f);
    gemm256<<<384, 512, 0, stream>>>(xb, wqkvT, qkv, Vt);
    dsum_kernel<<<512, 256, 0, stream>>>(qkv, negL);
    attn2_kernel<<<512, 256, 0, stream>>>(qkv, Vt, negL, ctx);
    gemm_bt<0><<<512, 256, 0, stream>>>(ctx, woT, (void*)out, b_out, 8192, 1024, 1024, 8, 64, 3072);
}

// Round 18
// 192.506 us; speedup vs baseline: 1.0045x; 1.0045x over previous
//
#include <hip/hip_runtime.h>
#include <hip/hip_bf16.h>

typedef __attribute__((ext_vector_type(8))) short short8;
typedef __attribute__((ext_vector_type(4))) short short4e;
typedef __attribute__((ext_vector_type(4))) float f32x4;
typedef __attribute__((ext_vector_type(16))) float f32x16;
typedef __attribute__((ext_vector_type(4))) unsigned uint4v;

#define SC_LOG2E 0.04508422f   // (1/32) * log2(e)
#define MFMA32(a, b, c) __builtin_amdgcn_mfma_f32_32x32x16_bf16(a, b, c, 0, 0, 0)

__device__ inline short bf16r(float f) {
    union { float f; unsigned u; } v; v.f = f;
    unsigned r = v.u + 0x7FFFu + ((v.u >> 16) & 1u);
    return (short)(r >> 16);
}
__device__ inline float bflo(unsigned u) {
    union { unsigned u; float f; } v; v.u = u << 16; return v.f;
}
__device__ inline float bfhi(unsigned u) {
    union { unsigned u; float f; } v; v.u = u & 0xffff0000u; return v.f;
}
// fast 2^x: single v_exp_f32, no libm range fixup (|x| < 40 in all our uses)
#if __has_builtin(__builtin_amdgcn_exp2f)
__device__ inline float fexp2(float x) { return __builtin_amdgcn_exp2f(x); }
#else
__device__ inline float fexp2(float x) { return __expf(x * 0.6931471806f); }
#endif
__device__ inline unsigned cvt_pk_bf16(float lo, float hi) {
    unsigned r;
    asm("v_cvt_pk_bf16_f32 %0, %1, %2" : "=v"(r) : "v"(lo), "v"(hi));
    return r;
}
// exchanges a.hi(lanes32-63) <-> b.lo(lanes0-31): a'=[a.lo,b.lo], b'=[a.hi,b.hi]
__device__ inline void perm32swap(unsigned& a, unsigned& b) {
    asm("v_permlane32_swap_b32 %0, %1" : "+v"(a), "+v"(b));
}

#define GLOAD_LDS16(gp, lp) __builtin_amdgcn_global_load_lds( \
    (const __attribute__((address_space(1))) unsigned int*)(gp), \
    (__attribute__((address_space(3))) unsigned int*)(lp), 16, 0, 0)

#define WB10 do { asm volatile("s_waitcnt vmcnt(10)\ns_barrier" ::: "memory"); __builtin_amdgcn_sched_barrier(0); } while (0)
#define WB4  do { asm volatile("s_waitcnt vmcnt(4)\ns_barrier"  ::: "memory"); __builtin_amdgcn_sched_barrier(0); } while (0)
#define WB0  do { asm volatile("s_waitcnt vmcnt(0)\ns_barrier"  ::: "memory"); __builtin_amdgcn_sched_barrier(0); } while (0)

// ---------------- elementwise cast fp32 -> bf16 ----------------
__global__ void castk(const float* __restrict__ in, short* __restrict__ out, int n4) {
    int i = blockIdx.x * 256 + threadIdx.x;
    if (i < n4) {
        float4 v = ((const float4*)in)[i];
        short4 o;
        o.x = bf16r(v.x); o.y = bf16r(v.y); o.z = bf16r(v.z); o.w = bf16r(v.w);
        ((short4*)out)[i] = o;
    }
}

// ---------------- transpose-cast fp32[R][C] -> bf16[C][R], rows < nscale scaled ----------------
__global__ void tcast(const float* __restrict__ src, short* __restrict__ dst, int R, int C,
                      int nscale, float sfac) {
    __shared__ float tile[32][33];
    int bi = blockIdx.x, bj = blockIdx.y;
    int tx = threadIdx.x & 31, ty = threadIdx.x >> 5;
#pragma unroll
    for (int p = 0; p < 4; p++)
        tile[ty + p * 8][tx] = src[(long)(bi * 32 + ty + p * 8) * C + bj * 32 + tx];
    __syncthreads();
#pragma unroll
    for (int p = 0; p < 4; p++) {
        int n = bj * 32 + ty + p * 8;                  // output channel (source column)
        float v = tile[tx][ty + p * 8];
        if (n < nscale) v *= sfac;
        dst[(long)n * R + bi * 32 + tx] = bf16r(v);
    }
}

// ---------------- gemm256: QKV projection, 256x256 tile, BK=64, 8-phase counted-vmcnt ------
// R18 fix: swizzle period — swz(row) = (row>>1)&3 (the R13-proven zero-conflict involution;
// R17's (row>>2)&3 left 4-row runs on one bank quad -> 4.7M conflicts). Both sides changed
// together (pre-swizzled global source + swizzled ds_read), layout stays self-consistent.
__global__ __launch_bounds__(512, 2)
void gemm256(const short* __restrict__ A, const short* __restrict__ Bt,
             short* __restrict__ qkv, short* __restrict__ Vt) {
    __shared__ short lds[65536];
    const int wg = blockIdx.x;
    const int lg = (wg & 7) * 48 + (wg >> 3);          // 384 blocks, bijective XCD chunk
    const int bx = lg % 12, by = lg / 12;
    const int m0 = by * 256, n0 = bx * 256;
    const int tid = threadIdx.x, w = tid >> 6, lane = tid & 63;
    const int wm = w >> 2, wn = w & 3;
    const int l15 = lane & 15, lhi = lane >> 4;
    f32x4 acc[8][4] = {};

    auto stA = [&](int t, int ks) {
#pragma unroll
        for (int j = 0; j < 2; j++) {
            int c = j * 512 + tid;
            int row = c >> 2, sl = c & 3;
            GLOAD_LDS16(A + (long)(m0 + row) * 1024 + t * 64 + ks * 32 + ((sl ^ ((row >> 1) & 3)) * 8),
                        &lds[((t & 1) * 2 + ks) * 8192 + c * 8]);
        }
    };
    auto stB = [&](int t, int ks) {
#pragma unroll
        for (int j = 0; j < 2; j++) {
            int c = j * 512 + tid;
            int row = c >> 2, sl = c & 3;
            GLOAD_LDS16(Bt + (long)(n0 + row) * 1024 + t * 64 + ks * 32 + ((sl ^ ((row >> 1) & 3)) * 8),
                        &lds[32768 + ((t & 1) * 2 + ks) * 8192 + c * 8]);
        }
    };

    short8 af[8], bf[2];
    auto ldA = [&](int buf, int ks) {
#pragma unroll
        for (int fi = 0; fi < 8; fi++) {
            int row = wm * 128 + fi * 16 + l15;
            af[fi] = *(const short8*)(&lds[(buf * 2 + ks) * 8192 + row * 32 +
                                           ((lhi ^ ((row >> 1) & 3)) * 8)]);
        }
    };
    auto ldB = [&](int buf, int ks, int fh) {
#pragma unroll
        for (int u = 0; u < 2; u++) {
            int row = wn * 64 + (fh * 2 + u) * 16 + l15;
            bf[u] = *(const short8*)(&lds[32768 + (buf * 2 + ks) * 8192 + row * 32 +
                                          ((lhi ^ ((row >> 1) & 3)) * 8)]);
        }
    };
    auto mm = [&](int fh) {
        __builtin_amdgcn_s_setprio(1);
#pragma unroll
        for (int fi = 0; fi < 8; fi++)
#pragma unroll
            for (int u = 0; u < 2; u++)
                acc[fi][fh * 2 + u] = __builtin_amdgcn_mfma_f32_16x16x32_bf16(
                    af[fi], bf[u], acc[fi][fh * 2 + u], 0, 0, 0);
        __builtin_amdgcn_s_setprio(0);
    };

    // prologue: mirrors steady-state phases 2..7 of iteration -1 (order matters for vmcnt)
    stA(0, 0); stB(0, 0); stA(0, 1); stB(0, 1); stA(1, 0); stB(1, 0);

    for (int i = 0; i < 8; i++) {
        const int t0 = 2 * i;
        // p0: compute tile t0 ks0 fj-half0
        stA(t0 + 1, 1); WB10;
        ldA(0, 0); ldB(0, 0, 0); mm(0);
        // p1
        stB(t0 + 1, 1); WB10;
        ldB(0, 0, 1); mm(1);
        // p2: tile t0 ks1
        if (i < 7) stA(t0 + 2, 0);
        WB10;
        ldA(0, 1); ldB(0, 1, 0); mm(0);
        // p3
        if (i < 7) stB(t0 + 2, 0);
        WB10;
        ldB(0, 1, 1); mm(1);
        // p4: tile t0+1 ks0
        if (i < 7) { stA(t0 + 2, 1); WB10; } else { WB4; }
        ldA(1, 0); ldB(1, 0, 0); mm(0);
        // p5
        if (i < 7) { stB(t0 + 2, 1); WB10; } else { WB4; }
        ldB(1, 0, 1); mm(1);
        // p6: tile t0+1 ks1
        if (i < 7) { stA(t0 + 3, 0); WB10; } else { WB0; }
        ldA(1, 1); ldB(1, 1, 0); mm(0);
        // p7
        if (i < 7) { stB(t0 + 3, 0); WB10; } else { WB0; }
        ldB(1, 1, 1); mm(1);
    }

    if (n0 >= 2048) {
        // V columns -> Vt[a][col'][k] directly (replaces vtrans)
        const int a = m0 >> 10, k0v = m0 & 1023;
#pragma unroll
        for (int fi = 0; fi < 8; fi++)
#pragma unroll
            for (int fj = 0; fj < 4; fj++) {
                int colp = n0 - 2048 + wn * 64 + fj * 16 + l15;
                int k = k0v + wm * 128 + fi * 16 + lhi * 4;
                short4e s4;
#pragma unroll
                for (int r = 0; r < 4; r++) s4[r] = bf16r(acc[fi][fj][r]);
                *(short4e*)(Vt + (long)a * 1048576 + (long)colp * 1024 + k) = s4;
            }
    } else {
#pragma unroll
        for (int fi = 0; fi < 8; fi++)
#pragma unroll
            for (int fj = 0; fj < 4; fj++)
#pragma unroll
                for (int r = 0; r < 4; r++) {
                    int row = m0 + wm * 128 + fi * 16 + lhi * 4 + r;
                    int col = n0 + wn * 64 + fj * 16 + l15;
                    qkv[(long)row * 3072 + col] = bf16r(acc[fi][fj][r]);
                }
    }
}

// ---------------- bf16 GEMM (128^2, R16-proven): used for the output projection -----------
template<int OUT_BF16>
__global__ __launch_bounds__(256, 3)
void gemm_bt(const short* __restrict__ A, const short* __restrict__ Bt,
             void* __restrict__ Cout, const float* __restrict__ bias,
             int M, int N, int K, int nbx, int cpx, int lda) {
    __shared__ short As[3][128 * 32];
    __shared__ short Bs[3][128 * 32];
    const int wg = blockIdx.x;
    const int lg = (wg & 7) * cpx + (wg >> 3);
    const int bx = lg % nbx, by = lg / nbx;
    const int tid = threadIdx.x, w = tid >> 6, lane = tid & 63;
    const int wr = w >> 1, wc = w & 1;
    const int l15 = lane & 15, lhi = lane >> 4;
    const int m0 = by * 128, n0 = bx * 128;
    f32x4 acc[4][4] = {};
    const int NT = K / 32;

    auto stage = [&](int buf, int t) {
        int k0 = t * 32;
#pragma unroll
        for (int j = 0; j < 2; j++) {
            int chunk = w * 128 + j * 64 + lane;
            int row = chunk >> 2, cp = chunk & 3;
            int cc = cp ^ ((row >> 1) & 3);            // pre-swizzled global k-chunk
            GLOAD_LDS16(A  + (long)(m0 + row) * lda + k0 + cc * 8, &As[buf][chunk * 8]);
            GLOAD_LDS16(Bt + (long)(n0 + row) * K   + k0 + cc * 8, &Bs[buf][chunk * 8]);
        }
    };

    stage(0, 0);
    stage(1, 1);
    asm volatile("s_waitcnt vmcnt(4)\ns_barrier" ::: "memory");
    __builtin_amdgcn_sched_barrier(0);

    int bR = 0, bW = 2;
    for (int t = 0; t < NT; t++) {
        bool issued = (t + 2 < NT);
        if (issued) stage(bW, t + 2);
        const short* Ab = As[bR];
        const short* Bb = Bs[bR];
        short8 af[4], bfr[4];
#pragma unroll
        for (int i = 0; i < 4; i++) {
            int arow = wr * 64 + i * 16 + l15;
            int brow = wc * 64 + i * 16 + l15;
            af[i]  = *(const short8*)(Ab + arow * 32 + (lhi ^ ((arow >> 1) & 3)) * 8);
            bfr[i] = *(const short8*)(Bb + brow * 32 + (lhi ^ ((brow >> 1) & 3)) * 8);
        }
        __builtin_amdgcn_s_setprio(1);
#pragma unroll
        for (int i = 0; i < 4; i++)
#pragma unroll
            for (int j = 0; j < 4; j++)
                acc[i][j] = __builtin_amdgcn_mfma_f32_16x16x32_bf16(af[i], bfr[j], acc[i][j], 0, 0, 0);
        __builtin_amdgcn_s_setprio(0);
        if (issued) asm volatile("s_waitcnt vmcnt(4)\ns_barrier" ::: "memory");
        else        asm volatile("s_waitcnt vmcnt(0)\ns_barrier" ::: "memory");
        __builtin_amdgcn_sched_barrier(0);
        bR = (bR == 2) ? 0 : bR + 1;
        bW = (bW == 2) ? 0 : bW + 1;
    }
#pragma unroll
    for (int i = 0; i < 4; i++)
#pragma unroll
        for (int j = 0; j < 4; j++)
#pragma unroll
            for (int r = 0; r < 4; r++) {
                int row = m0 + wr * 64 + i * 16 + lhi * 4 + r;
                int col = n0 + wc * 64 + j * 16 + l15;
                float v = acc[i][j][r];
                if (OUT_BF16) ((short*)Cout)[(long)row * N + col] = bf16r(v);
                else          ((float*)Cout)[(long)row * N + col] = v + bias[col];
            }
}

// ---------------- Phase A: negL packed-bf16 pairs, fragment-major ----------------
// word u of frag (a,ktg,qtg,lane): lo=-log2 D at reg 2u, hi at reg 2u+1;
// reg r -> (k = ktg*32 + (r&3)+8*(r>>2)+4*(lane>>5), q = qtg*32 + (lane&31))
__global__ __launch_bounds__(256, 2)
void dsum_kernel(const short* __restrict__ qkv, unsigned* __restrict__ negL) {
    __shared__ short Qs[2][128 * 64];
    __shared__ short Ks[2][128 * 64];
    const int wg = blockIdx.x;
    const int lg = (wg & 7) * 64 + (wg >> 3);
    const int a = lg >> 6, q0 = ((lg >> 3) & 7) * 128, k0 = (lg & 7) * 128;
    const int tid = threadIdx.x, w = tid >> 6, lane = tid & 63;
    const int wr = w >> 1, wc = w & 1;                 // wr: k-half, wc: q-half
    const int l31 = lane & 31, hi = lane >> 5;
    const long qb = (long)a * 3145728;
    f32x16 dacc[2][2] = {};

    auto stage = [&](int buf, int hh) {
#pragma unroll
        for (int j = 0; j < 4; j++) {
            int c = j * 256 + tid;
            int row = c >> 3, cc = (c & 7) ^ (row & 7);
            GLOAD_LDS16(qkv + qb + (long)(q0 + row) * 3072 + hh * 64 + cc * 8,        &Qs[buf][c * 8]);
            GLOAD_LDS16(qkv + qb + (long)(k0 + row) * 3072 + 1024 + hh * 64 + cc * 8, &Ks[buf][c * 8]);
        }
    };

    stage(0, 0);
    __syncthreads();
    int buf = 0;
    for (int hh = 0; hh < 16; hh++) {
        if (hh < 15) stage(buf ^ 1, hh + 1);
        short8 ka[2][4], qf[2][4];
#pragma unroll
        for (int i = 0; i < 2; i++)
#pragma unroll
            for (int dc = 0; dc < 4; dc++) {
                int row = wr * 64 + i * 32 + l31;
                int ph = (dc * 2 + hi) ^ (row & 7);
                ka[i][dc] = *(const short8*)(&Ks[buf][row * 64 + ph * 8]);
            }
#pragma unroll
        for (int j = 0; j < 2; j++)
#pragma unroll
            for (int dc = 0; dc < 4; dc++) {
                int row = wc * 64 + j * 32 + l31;
                int ph = (dc * 2 + hi) ^ (row & 7);
                qf[j][dc] = *(const short8*)(&Qs[buf][row * 64 + ph * 8]);
            }
#pragma unroll
        for (int i = 0; i < 2; i++)
#pragma unroll
            for (int j = 0; j < 2; j++) {
                f32x16 s = {};
#pragma unroll
                for (int dc = 0; dc < 4; dc++)
                    s = MFMA32(ka[i][dc], qf[j][dc], s);
#pragma unroll
                for (int r = 0; r < 16; r++)
                    dacc[i][j][r] += fexp2(s[r]);      // Q pre-scaled: s already log2-domain
            }
        __syncthreads();
        buf ^= 1;
    }
#pragma unroll
    for (int i = 0; i < 2; i++)
#pragma unroll
        for (int j = 0; j < 2; j++) {
            int ktg = (k0 >> 5) + wr * 2 + i;
            int qtg = (q0 >> 5) + wc * 2 + j;
            unsigned pwv[8];
#pragma unroll
            for (int u = 0; u < 8; u++)
                pwv[u] = cvt_pk_bf16(-__log2f(dacc[i][j][2 * u]),
                                     -__log2f(dacc[i][j][2 * u + 1]));
            unsigned* dst = negL + (((long)(a * 32 + ktg) * 32 + qtg) << 9) + lane * 8;
            *(uint4v*)dst       = (uint4v){pwv[0], pwv[1], pwv[2], pwv[3]};
            *(uint4v*)(dst + 4) = (uint4v){pwv[4], pwv[5], pwv[6], pwv[7]};
        }
}

// ---------------- Phase B: shared fragment-order staging + depth-2 counted-vmcnt ----------
__global__ __launch_bounds__(256, 2)
void attn2_kernel(const short* __restrict__ qkv, const short* __restrict__ Vt,
                  const unsigned* __restrict__ negL, short* __restrict__ ctx) {
    __shared__ short lds[3 * 8192];
    const int wg = blockIdx.x;
    const int lg = (wg & 7) * 64 + (wg >> 3);          // one batch per XCD
    const int a = lg >> 6, h = (lg >> 2) & 15, qblk = lg & 3;
    const int tid = threadIdx.x, w = tid >> 6, lane = tid & 63;
    const int l31 = lane & 31, hi = lane >> 5;
    const int qw = qblk * 256 + w * 64;
    const long qb = (long)a * 3145728;

    // Q fragments (B-operand, pre-scaled by (1/32)*log2e at tcast time)
    short8 qfrag[2][4];
#pragma unroll
    for (int qs = 0; qs < 2; qs++)
#pragma unroll
        for (int dc = 0; dc < 4; dc++)
            qfrag[qs][dc] = *(const short8*)(qkv + qb +
                (long)(qw + qs * 32 + l31) * 3072 + h * 64 + dc * 16 + hi * 8);

    const short* kcol  = qkv + qb + 1024 + h * 64;
    const short* vbase = Vt + (long)a * 1048576 + (long)(h * 64) * 1024;
    const unsigned* lbase = negL + (long)a * 524288 + (qw >> 5) * 512 + lane * 8;

    auto stage = [&](int buf, int t) {
        int k0 = t * 64;
#pragma unroll
        for (int j = 0; j < 2; j++) {
            GLOAD_LDS16(kcol + (long)(k0 + j * 32 + l31) * 3072 + w * 16 + hi * 8,
                        &lds[buf * 8192 + (j * 256 + tid) * 8]);
            int fidx = j * 4 + w, n = fidx >> 1, dt = fidx & 1;
            GLOAD_LDS16(vbase + (long)(dt * 32 + l31) * 1024 + k0 + n * 16 + hi * 8,
                        &lds[buf * 8192 + 4096 + (j * 256 + tid) * 8]);
        }
    };

    f32x16 oacc[2][2] = {};   // [qs][dt]
    stage(0, 0);
    stage(1, 1);
    asm volatile("s_waitcnt vmcnt(4)\ns_barrier" ::: "memory");
    __builtin_amdgcn_sched_barrier(0);

    int bR = 0, bW = 2;
    for (int t = 0; t < 16; t++) {
        uint4v dm[2][2][2];
#pragma unroll
        for (int qs = 0; qs < 2; qs++)
#pragma unroll
            for (int kt = 0; kt < 2; kt++) {
                const unsigned* dp = lbase + (long)(t * 2 + kt) * 16384 + qs * 512;
                dm[qs][kt][0] = *(const uint4v*)dp;
                dm[qs][kt][1] = *(const uint4v*)(dp + 4);
            }
        if (t + 2 < 16) stage(bW, t + 2);

        const short* Kb = &lds[bR * 8192];
        const short* Vb = &lds[bR * 8192 + 4096];
#pragma unroll
        for (int kt = 0; kt < 2; kt++) {
            short8 ka[4];
#pragma unroll
            for (int dc = 0; dc < 4; dc++)
                ka[dc] = *(const short8*)(Kb + ((kt * 4 + dc) * 64 + lane) * 8);

            short8 pf[2][2];   // [qs][nn]
#pragma unroll
            for (int qs = 0; qs < 2; qs++) {
                f32x16 s = {};
                __builtin_amdgcn_s_setprio(1);
#pragma unroll
                for (int dc = 0; dc < 4; dc++)
                    s = MFMA32(ka[dc], qfrag[qs][dc], s);
                __builtin_amdgcn_s_setprio(0);
                unsigned pw[8];
#pragma unroll
                for (int u = 0; u < 8; u++) {
                    unsigned d = dm[qs][kt][u >> 2][u & 3];
                    float e0 = fexp2(s[2 * u]     + bflo(d));
                    float e1 = fexp2(s[2 * u + 1] + bfhi(d));
                    pw[u] = cvt_pk_bf16(e0, e1);
                }
                perm32swap(pw[0], pw[2]); perm32swap(pw[1], pw[3]);
                perm32swap(pw[4], pw[6]); perm32swap(pw[5], pw[7]);
                union { uint4v u; short8 s8; } c0, c1;
                c0.u = (uint4v){pw[0], pw[1], pw[2], pw[3]};
                c1.u = (uint4v){pw[4], pw[5], pw[6], pw[7]};
                pf[qs][0] = c0.s8;
                pf[qs][1] = c1.s8;
            }
            __builtin_amdgcn_s_setprio(1);
#pragma unroll
            for (int dt = 0; dt < 2; dt++)
#pragma unroll
                for (int nn = 0; nn < 2; nn++) {
                    short8 vf = *(const short8*)(Vb + (((kt * 2 + nn) * 2 + dt) * 64 + lane) * 8);
#pragma unroll
                    for (int qs = 0; qs < 2; qs++)
                        oacc[qs][dt] = MFMA32(pf[qs][nn], vf, oacc[qs][dt]);
                }
            __builtin_amdgcn_s_setprio(0);
        }
        asm volatile("s_waitcnt vmcnt(4)\ns_barrier" ::: "memory");
        __builtin_amdgcn_sched_barrier(0);
        bR = (bR == 2) ? 0 : bR + 1;
        bW = (bW == 2) ? 0 : bW + 1;
    }
    // epilogue: ctx aliases qkv V-columns (lda 3072)
#pragma unroll
    for (int qs = 0; qs < 2; qs++)
#pragma unroll
        for (int dt = 0; dt < 2; dt++)
#pragma unroll
            for (int r = 0; r < 16; r++) {
                int q = qw + qs * 32 + (r & 3) + 8 * (r >> 2) + 4 * hi;
                int col = h * 64 + dt * 32 + l31;
                ctx[((long)a * 1024 + q) * 3072 + col] = bf16r(oacc[qs][dt][r]);
            }
}

extern "C" void kernel_launch(void* const* d_in, const int* in_sizes, int n_in,
                              void* d_out, int out_size, void* d_ws, size_t ws_size,
                              hipStream_t stream) {
    const float* x     = (const float*)d_in[0];
    const float* w_qkv = (const float*)d_in[1];
    const float* w_out = (const float*)d_in[2];
    const float* b_out = (const float*)d_in[3];
    float* out = (float*)d_out;

    char* ws = (char*)d_ws;
    short* wqkvT   = (short*)(ws);                // [0,6MB)   dead after gemm1
    unsigned* negL = (unsigned*)(ws);             // [0,16MB)  packed bf16 pairs (over wqkvT,
                                                  //           written by dsum AFTER gemm1)
    short* xb    = (short*)(ws + 16777216);       // [16,32MB) x bf16
    short* woT   = (short*)(ws + 33554432);       // [32,34MB) persists to gemm2
    short* qkv   = (short*)(ws + 35651584);       // [34,82MB) qkv bf16 [8192][3072]
    short* Vt    = (short*)(ws + 85983232);       // [82,98MB) V^T bf16 [8][1024][1024]
    short* ctx   = qkv + 2048;                    // aliases qkv V-columns, lda 3072
    if (ws_size < 109051904u) return;

    castk<<<8192, 256, 0, stream>>>(x, xb, 2097152);
    tcast<<<dim3(32, 96), 256, 0, stream>>>(w_qkv, wqkvT, 1024, 3072, 1024, SC_LOG2E);
    tcast<<<dim3(32, 32), 256, 0, stream>>>(w_out, woT, 1024, 1024, 0, 1.0f);
    gemm256<<<384, 512, 0, stream>>>(xb, wqkvT, qkv, Vt);
    dsum_kernel<<<512, 256, 0, stream>>>(qkv, negL);
    attn2_kernel<<<512, 256, 0, stream>>>(qkv, Vt, negL, ctx);
    gemm_bt<0><<<512, 256, 0, stream>>>(ctx, woT, (void*)out, b_out, 8192, 1024, 1024, 8, 64, 3072);
}